// Round 9
// baseline (213.808 us; speedup 1.0000x reference)
//
#include <hip/hip_runtime.h>
#include <math.h>

typedef unsigned short u16;
typedef unsigned int   u32;
typedef __attribute__((ext_vector_type(8))) short bf16x8;
typedef __attribute__((ext_vector_type(4))) float floatx4;
typedef __attribute__((ext_vector_type(4))) _Float16 halfx4;
typedef __attribute__((ext_vector_type(2))) unsigned int uintx2;

// B=2, S=2048, D=1024, H=16, Dh=64, M=B*S=4096
#define SEQ 2048
#define DM  1024
#define NH  16
#define DH  64
#define MM  4096
#define QSCALE 0.18033688011112042f   // 0.125 * log2(e), folded into Q

__device__ __forceinline__ u16 f2bf(float f) {
    u32 u = __builtin_bit_cast(u32, f);
    u += 0x7fffu + ((u >> 16) & 1u);
    return (u16)(u >> 16);
}

__device__ __forceinline__ void async16(const void* g, void* l) {
    __builtin_amdgcn_global_load_lds(
        (const __attribute__((address_space(1))) void*)g,
        (__attribute__((address_space(3))) void*)l, 16, 0, 0);
}

// ---------------- fp32 -> bf16 convert into MFMA-fragment-shuffled layout -------------
// Shuffled layout: tile (rowblk=row/16, ktile=col/32); element [m=lm][k=quad*8+j]
// stored flat at (rowblk*32 + ktile)*512 + lane*8 + j. One dwordx4/lane per fragment.
__global__ __launch_bounds__(256) void cvt_shuf(const float* __restrict__ x,
                                                const float* __restrict__ w0,
                                                const float* __restrict__ w1,
                                                const float* __restrict__ w2,
                                                const float* __restrict__ w3,
                                                u16* __restrict__ Xsh,
                                                u16* __restrict__ Wsh) {
    const int bid = blockIdx.x, cb = blockIdx.y, tid = threadIdx.x;
    const float* src; u16* dst; int row0;
    if (bid < 64) { src = x; dst = Xsh; row0 = bid * 64; }
    else {
        int wi = (bid - 64) >> 4;
        src = (wi == 0) ? w0 : (wi == 1) ? w1 : (wi == 2) ? w2 : w3;
        dst = Wsh + (size_t)wi * DM * DM;
        row0 = ((bid - 64) & 15) * 64;
    }
    __shared__ __align__(16) u16 t[64 * 64];   // 8-elem chunks XOR-swizzled by row&7
#pragma unroll
    for (int rep = 0; rep < 4; ++rep) {
        int f = rep * 256 + tid;
        int r = f >> 4, c4 = f & 15;
        float4 v = *(const float4*)&src[(size_t)(row0 + r) * DM + cb * 64 + c4 * 4];
        uint2 pk;
        pk.x = (u32)f2bf(v.x) | ((u32)f2bf(v.y) << 16);
        pk.y = (u32)f2bf(v.z) | ((u32)f2bf(v.w) << 16);
        int ch = (c4 >> 1) ^ (r & 7);
        *(uint2*)&t[r * 64 + ch * 8 + (c4 & 1) * 4] = pk;
    }
    __syncthreads();
#pragma unroll
    for (int rep = 0; rep < 2; ++rep) {
        int s = rep * 256 + tid;
        int tile = s >> 6, l = s & 63;
        int mt = tile >> 1, kt = tile & 1, lm = l & 15, quad = l >> 4;
        int m = mt * 16 + lm;
        uint4 v = *(const uint4*)&t[m * 64 + ((kt * 4 + quad) ^ (m & 7)) * 8];
        size_t rowblk = (size_t)(row0 >> 4) + mt;
        size_t ktile  = cb * 2 + kt;
        *(uint4*)&dst[(rowblk * 32 + ktile) * 512 + l * 8] = v;
    }
}

// ---------------- RoPE table: tab[pos][d2] = (cos, sin), 2048 x 32 ----------------
__global__ void rope_tab_kernel(const int* __restrict__ pos, float2* __restrict__ tab) {
    int i = blockIdx.x * 256 + threadIdx.x;   // 65536
    int p = i >> 5, d2 = i & 31;
    float freq = __expf(-(float)d2 * (9.2103403719761836f / 32.0f));
    float sv, cv;
    sincosf((float)pos[p] * freq, &sv, &cv);
    tab[i] = make_float2(cv, sv);
}

// ---------------- V transpose + f16 convert: V[b,s,h*64+d] -> Vt[(b*16+h)*64+d][s] ----
__global__ __launch_bounds__(256) void transpose_v(const u16* __restrict__ V, _Float16* __restrict__ Vt) {
    const int s0 = blockIdx.x * 64;
    const int b = blockIdx.y >> 4, h = blockIdx.y & 15;
    const int tid = threadIdx.x;
    __shared__ __align__(16) u16 t[64 * 72];
#pragma unroll
    for (int rep = 0; rep < 2; ++rep) {
        int f = rep * 256 + tid;
        int row = f >> 3, cc = (f & 7) * 8;
        *(uint4*)&t[row * 72 + cc] =
            *(const uint4*)&V[(size_t)(b * SEQ + s0 + row) * DM + h * DH + cc];
    }
    __syncthreads();
#pragma unroll
    for (int rep = 0; rep < 2; ++rep) {
        int f = rep * 256 + tid;
        int drow = f >> 3, cc = (f & 7) * 8;
        _Float16 o[8];
#pragma unroll
        for (int j = 0; j < 8; ++j) {
            u32 bits = (u32)t[(cc + j) * 72 + drow] << 16;
            o[j] = (_Float16)__builtin_bit_cast(float, bits);
        }
        *(uint4*)&Vt[(size_t)((b * NH + h) * DH + drow) * SEQ + s0 + cc] = *(uint4*)o;
    }
}

// ---------------- NT GEMM, NO-LDS: C[M,1024] = A * W^T, shuffled operands -----------
// 64 x (NT*64) block tile, 4 waves; wave w owns n-slice [n0 + w*NT*16, +NT*16).
// Register PING-PONG double buffer (two named sets, no copies), zero LDS/barriers.
template<int NT, bool OUTF32>
__global__ __launch_bounds__(256, 2) void gemm_nl(const u16* __restrict__ Ash,
                                                  const u16* __restrict__ Wbase,
                                                  u16* __restrict__ outbf,
                                                  float* __restrict__ outf,
                                                  const float2* __restrict__ ropetab,
                                                  int ropeMask) {
    const int z  = blockIdx.z;
    const u16* Wp = Wbase + (size_t)z * (DM * DM);
    const int m0 = blockIdx.x * 64, n0 = blockIdx.y * (NT * 64);
    const int tid  = threadIdx.x;
    const int lane = tid & 63, w = tid >> 6;
    const int lm = lane & 15, quad = lane >> 4;

    const u16* aB = Ash + ((size_t)(m0 >> 4) * 32) * 512 + lane * 8;
    const u16* bB = Wp  + ((size_t)((n0 >> 4) + w * NT) * 32) * 512 + lane * 8;

    floatx4 acc[4][NT];
    const floatx4 z4 = {0.f, 0.f, 0.f, 0.f};
#pragma unroll
    for (int mt = 0; mt < 4; ++mt)
#pragma unroll
        for (int nt = 0; nt < NT; ++nt) acc[mt][nt] = z4;

    bf16x8 s0a[2][4], s0b[2][NT], s1a[2][4], s1b[2][NT];

    auto ld = [&](bf16x8 (&ar)[2][4], bf16x8 (&br)[2][NT], int it) {
        const size_t ko = (size_t)it * 1024;
#pragma unroll
        for (int ks = 0; ks < 2; ++ks) {
#pragma unroll
            for (int mt = 0; mt < 4; ++mt)
                ar[ks][mt] = *(const bf16x8*)(aB + (size_t)mt * 16384 + ko + ks * 512);
#pragma unroll
            for (int nt = 0; nt < NT; ++nt)
                br[ks][nt] = *(const bf16x8*)(bB + (size_t)nt * 16384 + ko + ks * 512);
        }
    };
    auto fm = [&](bf16x8 (&ar)[2][4], bf16x8 (&br)[2][NT]) {
#pragma unroll
        for (int ks = 0; ks < 2; ++ks)
#pragma unroll
            for (int mt = 0; mt < 4; ++mt)
#pragma unroll
                for (int nt = 0; nt < NT; ++nt)
                    acc[mt][nt] = __builtin_amdgcn_mfma_f32_16x16x32_bf16(ar[ks][mt], br[ks][nt], acc[mt][nt], 0, 0, 0);
    };

    ld(s0a, s0b, 0);
#pragma unroll 1
    for (int it = 0; it < 16; it += 2) {
        if (it + 1 < 16) ld(s1a, s1b, it + 1);
        fm(s0a, s0b);
        if (it + 2 < 16) ld(s0a, s0b, it + 2);
        fm(s1a, s1b);
    }

    const bool rope = OUTF32 ? false : (((ropeMask >> z) & 1) != 0);
    const float osc = (!OUTF32 && z == 0) ? QSCALE : 1.0f;

#pragma unroll
    for (int mt = 0; mt < 4; ++mt)
#pragma unroll
        for (int r = 0; r < 4; ++r) {
            int row = m0 + mt * 16 + quad * 4 + r;
#pragma unroll
            for (int nt = 0; nt < NT; ++nt) {
                int col = n0 + w * (NT * 16) + nt * 16 + lm;
                float v  = acc[mt][nt][r];
                if (rope) {
                    float pv = __shfl_xor(v, 1);
                    float2 cs = ropetab[(row & (SEQ - 1)) * 32 + ((col & 63) >> 1)];
                    v = (lm & 1) ? fmaf(pv, cs.y, v * cs.x) : fmaf(v, cs.x, -pv * cs.y);
                }
                v *= osc;
                if (OUTF32) {
                    outf[(size_t)row * DM + col] = v;
                } else {
                    float hv = __shfl_xor(v, 1);
                    if (!(lm & 1)) {
                        u32 pk = (u32)f2bf(v) | ((u32)f2bf(hv) << 16);
                        *(u32*)&outbf[(size_t)z * ((size_t)MM * DM) + (size_t)row * DM + col] = pk;
                    }
                }
            }
        }
}

// ---------------- causal flash attention, S^T formulation, double-buffered ----------
// q-tile 128, 8 waves x 16 q-rows; k-tile 128; P^T in registers; V^T f16.
// Epilogue writes AO in shuffled-fragment layout (for the no-LDS Wo GEMM).
__global__ __launch_bounds__(512) void attn_kernel(const u16* __restrict__ Q,
                                                   const u16* __restrict__ K,
                                                   const _Float16* __restrict__ Vt,
                                                   u16* __restrict__ AO) {
    const int u  = blockIdx.x;
    const int qt = (u < 256) ? (15 - (u >> 5)) : ((u >> 5) - 8);
    const int bh = u & 31;
    const int b  = bh >> 4, h = bh & 15;
    const int q0 = qt * 128;
    const int tid = threadIdx.x, w = tid >> 6, lane = tid & 63;
    const int lm = lane & 15, quad = lane >> 4;

    __shared__ __align__(16) u16      lsK[2][128 * 64];   // [key][dim], col-swizzled
    __shared__ __align__(16) _Float16 lsV[2][64 * 128];   // [dim][key], 16B-block swizzled

    bf16x8 qb[2];
#pragma unroll
    for (int ks = 0; ks < 2; ++ks)
        qb[ks] = *(const bf16x8*)
            &Q[(size_t)(b * SEQ + q0 + w * 16 + lm) * DM + h * DH + ks * 32 + quad * 8];

    const floatx4 z4 = {0.f, 0.f, 0.f, 0.f};
    floatx4 o[4];                 // O^T[d][q]: d = dt*16+quad*4+r, q = lm
#pragma unroll
    for (int dt = 0; dt < 4; ++dt) o[dt] = z4;
    float lsum = 0.f;

    const int qloc = w * 16 + lm;

    auto stageKV = [&](int buf, int kt) {
#pragma unroll
        for (int rep = 0; rep < 2; ++rep) {
            int f = rep * 512 + tid;
            int krow = f >> 3, kcb = (f & 7) ^ (krow & 7);
            async16(&K[(size_t)(b * SEQ + kt * 128 + krow) * DM + h * DH + kcb * 8],
                    &lsK[buf][f * 8]);
            int d = f >> 4, gbs = (f & 15) ^ ((d >> 1) & 7);
            async16(&Vt[(size_t)(bh * DH + d) * SEQ + kt * 128 + gbs * 8],
                    &lsV[buf][f * 8]);
        }
    };

    stageKV(0, 0);
    for (int kt = 0; kt <= qt; ++kt) {
        __syncthreads();
        if (kt < qt) stageKV((kt + 1) & 1, kt + 1);
        const u16*      Lk = lsK[kt & 1];
        const _Float16* Lv = lsV[kt & 1];

        floatx4 s4[8];
#pragma unroll
        for (int st = 0; st < 8; ++st) s4[st] = z4;
#pragma unroll
        for (int ks = 0; ks < 2; ++ks) {
            const int cbl = ((ks * 4 + quad) ^ (lm & 7)) * 8;
#pragma unroll
            for (int st = 0; st < 8; ++st) {
                bf16x8 ka = *(const bf16x8*)&Lk[(st * 16 + lm) * 64 + cbl];
                s4[st] = __builtin_amdgcn_mfma_f32_16x16x32_bf16(ka, qb[ks], s4[st], 0, 0, 0);
            }
        }

        halfx4 pb[8];
        const bool diag = (kt == qt);
#pragma unroll
        for (int st = 0; st < 8; ++st) {
#pragma unroll
            for (int r = 0; r < 4; ++r) {
                float v = s4[st][r];
                if (diag) {
                    int keyloc = st * 16 + quad * 4 + r;
                    if (keyloc > qloc) v = -1e30f;
                }
                v = exp2f(v);
                lsum += v;
                s4[st][r] = v;
            }
            uintx2 pk2;
            pk2.x = __builtin_bit_cast(u32, __builtin_amdgcn_cvt_pkrtz(s4[st][0], s4[st][1]));
            pk2.y = __builtin_bit_cast(u32, __builtin_amdgcn_cvt_pkrtz(s4[st][2], s4[st][3]));
            pb[st] = __builtin_bit_cast(halfx4, pk2);
        }

#pragma unroll
        for (int st = 0; st < 8; ++st) {
#pragma unroll
            for (int dt = 0; dt < 4; ++dt) {
                int drow = dt * 16 + lm;
                int sbs = (st * 2 + (quad >> 1)) ^ ((drow >> 1) & 7);
                halfx4 va = *(const halfx4*)&Lv[drow * 128 + sbs * 8 + (quad & 1) * 4];
                o[dt] = __builtin_amdgcn_mfma_f32_16x16x16f16(va, pb[st], o[dt], 0, 0, 0);
            }
        }
    }

    // row-sum across the 4 quads holding q = lm
    lsum += __shfl_xor(lsum, 16);
    lsum += __shfl_xor(lsum, 32);
    float rl = 1.0f / lsum;

    // epilogue: O^T (reg) -> LDS (swizzled natural [q][d]) -> shuffled-frag AO store
    __syncthreads();                       // all waves done with lsK/lsV
    u16* eb = (u16*)&lsK[0][0];            // 128x64 bf16 = 16 KB
    const int q = w * 16 + lm;
#pragma unroll
    for (int dt = 0; dt < 4; ++dt) {
        uint2 pk;
        pk.x = (u32)f2bf(o[dt][0] * rl) | ((u32)f2bf(o[dt][1] * rl) << 16);
        pk.y = (u32)f2bf(o[dt][2] * rl) | ((u32)f2bf(o[dt][3] * rl) << 16);
        int ch = (dt * 2 + (quad >> 1)) ^ (lm & 7);
        *(uint2*)&eb[q * 64 + ch * 8 + (quad & 1) * 4] = pk;
    }
    __syncthreads();
    const size_t rowblk = (size_t)((b * SEQ + q0) >> 4) + w;
#pragma unroll
    for (int kt = 0; kt < 2; ++kt) {
        uint4 v = *(const uint4*)&eb[(w * 16 + lm) * 64 + ((kt * 4 + quad) ^ (lm & 7)) * 8];
        *(uint4*)&AO[(rowblk * 32 + (h * 2 + kt)) * 512 + lane * 8] = v;
    }
}

extern "C" void kernel_launch(void* const* d_in, const int* in_sizes, int n_in,
                              void* d_out, int out_size, void* d_ws, size_t ws_size,
                              hipStream_t stream) {
    const float* x   = (const float*)d_in[0];
    const int*   pos = (const int*)d_in[1];
    float* out = (float*)d_out;

    u16* ws = (u16*)d_ws;
    const size_t MD = (size_t)MM * DM;
    const size_t DD = (size_t)DM * DM;
    u16* Xsh = ws;                        // shuffled X; dead after QKV -> reused as AOsh
    u16* Wsh = ws + MD;                   // 4 shuffled weights (q,k,v,o)
    u16* Qbf = ws + MD + 4 * DD;          // natural layouts
    u16* Kbf = Qbf + MD;
    u16* Vbf = Kbf + MD;
    u16* VtB = Vbf + MD;                  // f16 V^T
    float2* ropetab = (float2*)(VtB + MD);
    _Float16* Vt = (_Float16*)VtB;
    u16* AOsh = Xsh;

    cvt_shuf<<<dim3(128, 16), 256, 0, stream>>>(
        x, (const float*)d_in[2], (const float*)d_in[3], (const float*)d_in[4],
        (const float*)d_in[5], Xsh, Wsh);
    rope_tab_kernel<<<SEQ * 32 / 256, 256, 0, stream>>>(pos, ropetab);

    // Q/K/V projections + fused RoPE on Q,K; softmax scale folded into Q
    gemm_nl<2, false><<<dim3(64, 8, 3), 256, 0, stream>>>(Xsh, Wsh, Qbf, nullptr, ropetab, 0x3);

    // V -> Vt[b,h,d,s] in f16
    transpose_v<<<dim3(SEQ / 64, 2 * NH), 256, 0, stream>>>(Vbf, Vt);

    // causal flash attention (writes AO in shuffled-frag layout)
    attn_kernel<<<dim3(512), 512, 0, stream>>>(Qbf, Kbf, Vt, AOsh);

    // output projection -> fp32 d_out
    gemm_nl<2, true><<<dim3(64, 8, 1), 256, 0, stream>>>(AOsh, Wsh + 3 * DD, nullptr, out, nullptr, 0);
}

// Round 11
// 196.197 us; speedup vs baseline: 1.0898x; 1.0898x over previous
//
#include <hip/hip_runtime.h>
#include <math.h>

typedef unsigned short u16;
typedef unsigned int   u32;
typedef __attribute__((ext_vector_type(8))) short bf16x8;
typedef __attribute__((ext_vector_type(4))) float floatx4;
typedef __attribute__((ext_vector_type(4))) _Float16 halfx4;
typedef __attribute__((ext_vector_type(2))) unsigned int uintx2;

// B=2, S=2048, D=1024, H=16, Dh=64, M=B*S=4096
#define SEQ 2048
#define DM  1024
#define NH  16
#define DH  64
#define MM  4096
#define QSCALE 0.18033688011112042f   // 0.125 * log2(e), folded into Q

__device__ __forceinline__ u16 f2bf(float f) {
    u32 u = __builtin_bit_cast(u32, f);
    u += 0x7fffu + ((u >> 16) & 1u);
    return (u16)(u >> 16);
}

__device__ __forceinline__ void async16(const void* g, void* l) {
    __builtin_amdgcn_global_load_lds(
        (const __attribute__((address_space(1))) void*)g,
        (__attribute__((address_space(3))) void*)l, 16, 0, 0);
}

// ---------------- prep: fp32 -> bf16 shuffled layout + RoPE table -------------------
// Shuffled layout: tile (rowblk=row/16, ktile=col/32); element [m=lm][k=quad*8+j]
// stored flat at (rowblk*32 + ktile)*512 + lane*8 + j. One dwordx4/lane per fragment.
// First 256 linear blocks additionally fill the RoPE table (2048x32 float2).
__global__ __launch_bounds__(256) void prep_kernel(const float* __restrict__ x,
                                                   const float* __restrict__ w0,
                                                   const float* __restrict__ w1,
                                                   const float* __restrict__ w2,
                                                   const float* __restrict__ w3,
                                                   u16* __restrict__ Xsh,
                                                   u16* __restrict__ Wsh,
                                                   const int* __restrict__ pos,
                                                   float2* __restrict__ tab) {
    const int bid = blockIdx.x, cb = blockIdx.y, tid = threadIdx.x;

    // RoPE table side-job
    int lin = bid * 16 + cb;
    if (lin < 256) {
        int i = lin * 256 + tid;       // 65536 = 2048*32
        int p = i >> 5, d2 = i & 31;
        float freq = __expf(-(float)d2 * (9.2103403719761836f / 32.0f));
        float sv, cv;
        sincosf((float)pos[p] * freq, &sv, &cv);
        tab[i] = make_float2(cv, sv);
    }

    const float* src; u16* dst; int row0;
    if (bid < 64) { src = x; dst = Xsh; row0 = bid * 64; }
    else {
        int wi = (bid - 64) >> 4;
        src = (wi == 0) ? w0 : (wi == 1) ? w1 : (wi == 2) ? w2 : w3;
        dst = Wsh + (size_t)wi * DM * DM;
        row0 = ((bid - 64) & 15) * 64;
    }
    __shared__ __align__(16) u16 t[64 * 64];   // 8-elem chunks XOR-swizzled by row&7
#pragma unroll
    for (int rep = 0; rep < 4; ++rep) {
        int f = rep * 256 + tid;
        int r = f >> 4, c4 = f & 15;
        float4 v = *(const float4*)&src[(size_t)(row0 + r) * DM + cb * 64 + c4 * 4];
        uint2 pk;
        pk.x = (u32)f2bf(v.x) | ((u32)f2bf(v.y) << 16);
        pk.y = (u32)f2bf(v.z) | ((u32)f2bf(v.w) << 16);
        int ch = (c4 >> 1) ^ (r & 7);
        *(uint2*)&t[r * 64 + ch * 8 + (c4 & 1) * 4] = pk;
    }
    __syncthreads();
#pragma unroll
    for (int rep = 0; rep < 2; ++rep) {
        int s = rep * 256 + tid;
        int tile = s >> 6, l = s & 63;
        int mt = tile >> 1, kt = tile & 1, lm = l & 15, quad = l >> 4;
        int m = mt * 16 + lm;
        uint4 v = *(const uint4*)&t[m * 64 + ((kt * 4 + quad) ^ (m & 7)) * 8];
        size_t rowblk = (size_t)(row0 >> 4) + mt;
        size_t ktile  = cb * 2 + kt;
        *(uint4*)&dst[(rowblk * 32 + ktile) * 512 + l * 8] = v;
    }
}

// ---------------- NT GEMM, NO-LDS: C[M,1024] = A * W^T, shuffled operands -----------
// 64 x (NT*64) block tile, 4 waves; wave w owns n-slice [n0 + w*NT*16, +NT*16).
// r7-measured-best K-loop (compiler-scheduled prefetch). z==2 (V) writes V^T f16.
template<int NT, bool OUTF32>
__global__ __launch_bounds__(256) void gemm_nl(const u16* __restrict__ Ash,
                                               const u16* __restrict__ Wbase,
                                               u16* __restrict__ outbf,
                                               float* __restrict__ outf,
                                               _Float16* __restrict__ vtout,
                                               const float2* __restrict__ ropetab,
                                               int ropeMask) {
    const int z  = blockIdx.z;
    const u16* Wp = Wbase + (size_t)z * (DM * DM);
    const int m0 = blockIdx.x * 64, n0 = blockIdx.y * (NT * 64);
    const int tid  = threadIdx.x;
    const int lane = tid & 63, w = tid >> 6;
    const int lm = lane & 15, quad = lane >> 4;

    const u16* aB = Ash + ((size_t)(m0 >> 4) * 32) * 512 + lane * 8;
    const u16* bB = Wp  + ((size_t)((n0 >> 4) + w * NT) * 32) * 512 + lane * 8;

    floatx4 acc[4][NT];
    const floatx4 z4 = {0.f, 0.f, 0.f, 0.f};
#pragma unroll
    for (int mt = 0; mt < 4; ++mt)
#pragma unroll
        for (int nt = 0; nt < NT; ++nt) acc[mt][nt] = z4;

    bf16x8 ca[2][4], cb2[2][NT];
#pragma unroll
    for (int ks = 0; ks < 2; ++ks) {
#pragma unroll
        for (int mt = 0; mt < 4; ++mt)
            ca[ks][mt] = *(const bf16x8*)(aB + (size_t)mt * 16384 + ks * 512);
#pragma unroll
        for (int nt = 0; nt < NT; ++nt)
            cb2[ks][nt] = *(const bf16x8*)(bB + (size_t)nt * 16384 + ks * 512);
    }

#pragma unroll 2
    for (int it = 0; it < 16; ++it) {
        bf16x8 na[2][4], nb[2][NT];
        if (it < 15) {
            const size_t ko = (size_t)(it + 1) * 1024;
#pragma unroll
            for (int ks = 0; ks < 2; ++ks) {
#pragma unroll
                for (int mt = 0; mt < 4; ++mt)
                    na[ks][mt] = *(const bf16x8*)(aB + (size_t)mt * 16384 + ko + ks * 512);
#pragma unroll
                for (int nt = 0; nt < NT; ++nt)
                    nb[ks][nt] = *(const bf16x8*)(bB + (size_t)nt * 16384 + ko + ks * 512);
            }
        }
#pragma unroll
        for (int ks = 0; ks < 2; ++ks)
#pragma unroll
            for (int mt = 0; mt < 4; ++mt)
#pragma unroll
                for (int nt = 0; nt < NT; ++nt)
                    acc[mt][nt] = __builtin_amdgcn_mfma_f32_16x16x32_bf16(ca[ks][mt], cb2[ks][nt], acc[mt][nt], 0, 0, 0);
        if (it < 15) {
#pragma unroll
            for (int ks = 0; ks < 2; ++ks) {
#pragma unroll
                for (int mt = 0; mt < 4; ++mt) ca[ks][mt] = na[ks][mt];
#pragma unroll
                for (int nt = 0; nt < NT; ++nt) cb2[ks][nt] = nb[ks][nt];
            }
        }
    }

    if (!OUTF32 && z == 2) {
        // V slice: write V^T f16 directly: Vt[(b*NH+h)*DH + d][s]  (= b*1024 + col)
#pragma unroll
        for (int mt = 0; mt < 4; ++mt) {
            int row = m0 + mt * 16 + quad * 4;          // s0 (r=0..3 consecutive)
            int b = row >> 11, s = row & (SEQ - 1);
#pragma unroll
            for (int nt = 0; nt < NT; ++nt) {
                int col = n0 + w * (NT * 16) + nt * 16 + lm;   // h*64+d
                uint2 pk;
                pk.x = __builtin_bit_cast(u32, __builtin_amdgcn_cvt_pkrtz(acc[mt][nt][0], acc[mt][nt][1]));
                pk.y = __builtin_bit_cast(u32, __builtin_amdgcn_cvt_pkrtz(acc[mt][nt][2], acc[mt][nt][3]));
                *(uint2*)&vtout[((size_t)b * NH * DH + (size_t)col) * SEQ + s] = pk;
            }
        }
        return;
    }

    const bool rope = OUTF32 ? false : (((ropeMask >> z) & 1) != 0);
    const float osc = (!OUTF32 && z == 0) ? QSCALE : 1.0f;

#pragma unroll
    for (int mt = 0; mt < 4; ++mt)
#pragma unroll
        for (int r = 0; r < 4; ++r) {
            int row = m0 + mt * 16 + quad * 4 + r;
#pragma unroll
            for (int nt = 0; nt < NT; ++nt) {
                int col = n0 + w * (NT * 16) + nt * 16 + lm;
                float v  = acc[mt][nt][r];
                if (rope) {
                    float pv = __shfl_xor(v, 1);
                    float2 cs = ropetab[(row & (SEQ - 1)) * 32 + ((col & 63) >> 1)];
                    v = (lm & 1) ? fmaf(pv, cs.y, v * cs.x) : fmaf(v, cs.x, -pv * cs.y);
                }
                v *= osc;
                if (OUTF32) {
                    outf[(size_t)row * DM + col] = v;
                } else {
                    float hv = __shfl_xor(v, 1);
                    if (!(lm & 1)) {
                        u32 pk = (u32)f2bf(v) | ((u32)f2bf(hv) << 16);
                        *(u32*)&outbf[(size_t)z * ((size_t)MM * DM) + (size_t)row * DM + col] = pk;
                    }
                }
            }
        }
}

// ---------------- causal flash attention, S^T formulation, double-buffered ----------
// q-tile 128, 8 waves x 16 q-rows; k-tile 128; P^T in registers; V^T f16.
// Epilogue writes AO in shuffled-fragment layout (for the no-LDS Wo GEMM).
__global__ __launch_bounds__(512) void attn_kernel(const u16* __restrict__ Q,
                                                   const u16* __restrict__ K,
                                                   const _Float16* __restrict__ Vt,
                                                   u16* __restrict__ AO) {
    const int u  = blockIdx.x;
    const int qt = (u < 256) ? (15 - (u >> 5)) : ((u >> 5) - 8);
    const int bh = u & 31;
    const int b  = bh >> 4, h = bh & 15;
    const int q0 = qt * 128;
    const int tid = threadIdx.x, w = tid >> 6, lane = tid & 63;
    const int lm = lane & 15, quad = lane >> 4;

    __shared__ __align__(16) u16      lsK[2][128 * 64];   // [key][dim], col-swizzled
    __shared__ __align__(16) _Float16 lsV[2][64 * 128];   // [dim][key], 16B-block swizzled

    bf16x8 qb[2];
#pragma unroll
    for (int ks = 0; ks < 2; ++ks)
        qb[ks] = *(const bf16x8*)
            &Q[(size_t)(b * SEQ + q0 + w * 16 + lm) * DM + h * DH + ks * 32 + quad * 8];

    const floatx4 z4 = {0.f, 0.f, 0.f, 0.f};
    floatx4 o[4];                 // O^T[d][q]: d = dt*16+quad*4+r, q = lm
#pragma unroll
    for (int dt = 0; dt < 4; ++dt) o[dt] = z4;
    float lsum = 0.f;

    const int qloc = w * 16 + lm;

    auto stageKV = [&](int buf, int kt) {
#pragma unroll
        for (int rep = 0; rep < 2; ++rep) {
            int f = rep * 512 + tid;
            int krow = f >> 3, kcb = (f & 7) ^ (krow & 7);
            async16(&K[(size_t)(b * SEQ + kt * 128 + krow) * DM + h * DH + kcb * 8],
                    &lsK[buf][f * 8]);
            int d = f >> 4, gbs = (f & 15) ^ ((d >> 1) & 7);
            async16(&Vt[(size_t)(bh * DH + d) * SEQ + kt * 128 + gbs * 8],
                    &lsV[buf][f * 8]);
        }
    };

    stageKV(0, 0);
    for (int kt = 0; kt <= qt; ++kt) {
        __syncthreads();
        if (kt < qt) stageKV((kt + 1) & 1, kt + 1);
        const u16*      Lk = lsK[kt & 1];
        const _Float16* Lv = lsV[kt & 1];

        floatx4 s4[8];
#pragma unroll
        for (int st = 0; st < 8; ++st) s4[st] = z4;
#pragma unroll
        for (int ks = 0; ks < 2; ++ks) {
            const int cbl = ((ks * 4 + quad) ^ (lm & 7)) * 8;
#pragma unroll
            for (int st = 0; st < 8; ++st) {
                bf16x8 ka = *(const bf16x8*)&Lk[(st * 16 + lm) * 64 + cbl];
                s4[st] = __builtin_amdgcn_mfma_f32_16x16x32_bf16(ka, qb[ks], s4[st], 0, 0, 0);
            }
        }

        halfx4 pb[8];
        const bool diag = (kt == qt);
#pragma unroll
        for (int st = 0; st < 8; ++st) {
#pragma unroll
            for (int r = 0; r < 4; ++r) {
                float v = s4[st][r];
                if (diag) {
                    int keyloc = st * 16 + quad * 4 + r;
                    if (keyloc > qloc) v = -1e30f;
                }
                v = exp2f(v);
                lsum += v;
                s4[st][r] = v;
            }
            uintx2 pk2;
            pk2.x = __builtin_bit_cast(u32, __builtin_amdgcn_cvt_pkrtz(s4[st][0], s4[st][1]));
            pk2.y = __builtin_bit_cast(u32, __builtin_amdgcn_cvt_pkrtz(s4[st][2], s4[st][3]));
            pb[st] = __builtin_bit_cast(halfx4, pk2);
        }

#pragma unroll
        for (int st = 0; st < 8; ++st) {
#pragma unroll
            for (int dt = 0; dt < 4; ++dt) {
                int drow = dt * 16 + lm;
                int sbs = (st * 2 + (quad >> 1)) ^ ((drow >> 1) & 7);
                halfx4 va = *(const halfx4*)&Lv[drow * 128 + sbs * 8 + (quad & 1) * 4];
                o[dt] = __builtin_amdgcn_mfma_f32_16x16x16f16(va, pb[st], o[dt], 0, 0, 0);
            }
        }
    }

    // row-sum across the 4 quads holding q = lm
    lsum += __shfl_xor(lsum, 16);
    lsum += __shfl_xor(lsum, 32);
    float rl = 1.0f / lsum;

    // epilogue: O^T (reg) -> LDS (swizzled natural [q][d]) -> shuffled-frag AO store
    __syncthreads();                       // all waves done with lsK/lsV
    u16* eb = (u16*)&lsK[0][0];            // 128x64 bf16 = 16 KB
    const int q = w * 16 + lm;
#pragma unroll
    for (int dt = 0; dt < 4; ++dt) {
        uint2 pk;
        pk.x = (u32)f2bf(o[dt][0] * rl) | ((u32)f2bf(o[dt][1] * rl) << 16);
        pk.y = (u32)f2bf(o[dt][2] * rl) | ((u32)f2bf(o[dt][3] * rl) << 16);
        int ch = (dt * 2 + (quad >> 1)) ^ (lm & 7);
        *(uint2*)&eb[q * 64 + ch * 8 + (quad & 1) * 4] = pk;
    }
    __syncthreads();
    const size_t rowblk = (size_t)((b * SEQ + q0) >> 4) + w;
#pragma unroll
    for (int kt = 0; kt < 2; ++kt) {
        uint4 v = *(const uint4*)&eb[(w * 16 + lm) * 64 + ((kt * 4 + quad) ^ (lm & 7)) * 8];
        *(uint4*)&AO[(rowblk * 32 + (h * 2 + kt)) * 512 + lane * 8] = v;
    }
}

extern "C" void kernel_launch(void* const* d_in, const int* in_sizes, int n_in,
                              void* d_out, int out_size, void* d_ws, size_t ws_size,
                              hipStream_t stream) {
    const float* x   = (const float*)d_in[0];
    const int*   pos = (const int*)d_in[1];
    float* out = (float*)d_out;

    u16* ws = (u16*)d_ws;
    const size_t MD = (size_t)MM * DM;
    const size_t DD = (size_t)DM * DM;
    u16* Xsh = ws;                        // shuffled X; dead after QKV -> reused as AOsh
    u16* Wsh = ws + MD;                   // 4 shuffled weights (q,k,v,o)
    u16* Qbf = ws + MD + 4 * DD;          // natural layouts
    u16* Kbf = Qbf + MD;
    u16* VtB = Kbf + MD;                  // f16 V^T (written by QKV z==2 epilogue)
    float2* ropetab = (float2*)(VtB + MD);
    _Float16* Vt = (_Float16*)VtB;
    u16* AOsh = Xsh;

    // prep: bf16 shuffled X + 4 W, RoPE table (one launch)
    prep_kernel<<<dim3(128, 16), 256, 0, stream>>>(
        x, (const float*)d_in[2], (const float*)d_in[3], (const float*)d_in[4],
        (const float*)d_in[5], Xsh, Wsh, pos, ropetab);

    // Q/K/V projections; RoPE fused on Q,K; softmax scale folded into Q; V^T written directly
    gemm_nl<2, false><<<dim3(64, 8, 3), 256, 0, stream>>>(
        Xsh, Wsh, Qbf, nullptr, Vt, ropetab, 0x3);

    // causal flash attention (writes AO in shuffled-frag layout)
    attn_kernel<<<dim3(512), 512, 0, stream>>>(Qbf, Kbf, Vt, AOsh);

    // output projection -> fp32 d_out
    gemm_nl<2, true><<<dim3(64, 8, 1), 256, 0, stream>>>(
        AOsh, Wsh + 3 * DD, nullptr, out, nullptr, nullptr, 0);
}